// Round 8
// baseline (42.191 us; speedup 1.0000x reference)
//
#include <hip/hip_runtime.h>
#include <hip/hip_fp16.h>
#include <math.h>

// Radon forward, exact reference semantics (rotated-lattice bilinear gather).
//
// Round-14 changes vs round 13 (34.1 us total; tile7 ~29-30 us):
//  * Accounting: per-sample pipes now cheap (VALU ~5.7 us, LDS ~7.8 us);
//    wall dominated by 8,640 per-subtile stage events (vmcnt(0) drain +
//    2 barriers each). Lever = fewer, fatter events.
//  * Tile doubled: 64j x 48i, TS2=96 (mult of 32 -> bank-free kept),
//    TROWS=92 (span bound: rows <= 47|c|+63|s| <= 78 + ~6 pair-union
//    + 4 guard = 88, slack 4). NTILE 35,840 B -> 4 blocks/CU.
//  * 512-thread blocks: 8 waves = 2 angles x 4 j-groups(16) x 4 i-groups.
//    32 waves/CU. z=4 -> 2160 blocks x 2 subtiles: stage events halve
//    (8,640 -> 4,320), each hidden behind 2x gather work (96 wave-samples).
//  * Inner loop identical to r13 (packed-f16 lerp, tile-relative coords).

#define G       363
#define NT      180
#define PADB    53
#define STEP    (2.0f / 362.0f)
#define DEG2RAD 0.017453292519943295f

#define TS2     96          // tile row length (u32 cells), %32==0 (bank-free)
#define TROWS   92          // max tile rows
#define NCHK    35          // max staging chunks (256 cells = 1 KiB each)
#define NTILE   (NCHK * 256)   // 8960 cells = 35,840 B -> 4 blocks/CU
#define NJB     6           // j-blocks of 64
#define NIB     8           // i-subtiles of 48
#define NJBF    6           // fallback j-blocks of 64
#define CW      264         // canvas cols (4 guard + 256 + 4 guard)
#define CH      264         // canvas rows
#define NTUPLE  (90 * NJB * NIB)   // 4320

#define GLOAD16(gp, lp) __builtin_amdgcn_global_load_lds(                     \
    (const __attribute__((address_space(1))) void*)(gp),                      \
    (__attribute__((address_space(3))) void*)(lp), 16, 0, 0)

// ---------------- fallback gather kernel (known-good, round 1) -------------
__global__ __launch_bounds__(256) void radon_fwd(
    const float* __restrict__ x, const int* __restrict__ theta,
    float* __restrict__ out)
{
    const int t = blockIdx.x / NJBF, jb = blockIdx.x % NJBF;
    const int jl = threadIdx.x, chunk = threadIdx.y;
    const int j = jb * 64 + jl;
    const float th = (float)theta[t] * DEG2RAD;
    const float c = cosf(th), s = sinf(th);
    const float xj = fmaf((float)j, STEP, -1.0f);
    const float s181 = s * 181.0f, c181 = c * 181.0f;
    const float bx = fmaf(c, xj, 1.0f) * 181.0f;
    const float by = fmaf(-s, xj, 1.0f) * 181.0f;
    const float* img0 = x;
    const float* img1 = x + 65536;
    float acc0 = 0.f, acc1 = 0.f;
    for (int i = chunk; i < G; i += 4) {
        const float xi = fmaf((float)i, STEP, -1.0f);
        const float ix = fmaf(s181, xi, bx);
        const float iy = fmaf(c181, xi, by);
        const float fx = floorf(ix), fy = floorf(iy);
        const int ix0 = (int)fx, iy0 = (int)fy;
        const float wx1 = ix - fx, wy1 = iy - fy;
        const float wx0 = 1.f - wx1, wy0 = 1.f - wy1;
        const int cc0 = ix0 - 53, cc1 = cc0 + 1, rr0 = iy0 - 53, rr1 = rr0 + 1;
        const float wxa = ((unsigned)cc0 < 256u) ? wx0 : 0.f;
        const float wxb = ((unsigned)cc1 < 256u) ? wx1 : 0.f;
        const float wya = ((unsigned)rr0 < 256u) ? wy0 : 0.f;
        const float wyb = ((unsigned)rr1 < 256u) ? wy1 : 0.f;
        const int c0c = min(max(cc0, 0), 255), c1c = min(max(cc1, 0), 255);
        const int r0b = min(max(rr0, 0), 255) << 8, r1b = min(max(rr1, 0), 255) << 8;
        const float w00 = wya * wxa, w01 = wya * wxb, w10 = wyb * wxa, w11 = wyb * wxb;
        acc0 = fmaf(img0[r0b + c0c], w00, acc0);
        acc0 = fmaf(img0[r0b + c1c], w01, acc0);
        acc0 = fmaf(img0[r1b + c0c], w10, acc0);
        acc0 = fmaf(img0[r1b + c1c], w11, acc0);
        acc1 = fmaf(img1[r0b + c0c], w00, acc1);
        acc1 = fmaf(img1[r0b + c1c], w01, acc1);
        acc1 = fmaf(img1[r1b + c0c], w10, acc1);
        acc1 = fmaf(img1[r1b + c1c], w11, acc1);
    }
    __shared__ float red[2][4][64];
    red[0][chunk][jl] = acc0;
    red[1][chunk][jl] = acc1;
    __syncthreads();
    if (threadIdx.y < 2 && j < G) {
        const int n = threadIdx.y;
        out[n * (G * NT) + j * NT + t] =
            red[n][0][jl] + red[n][1][jl] + red[n][2][jl] + red[n][3][jl];
    }
}

// ------------- prep: f16x2 canvases + bbox table + zero(out) ---------------
// Block roles by blockIdx.x:
//   [0,81)   : pack image pair into guarded u32 canvases (normal+transposed)
//   [81,98)  : bbox table, one tuple (tg,jb,ib) per thread (4320 tuples)
//   [98,226) : zero out (32670 float4)
__global__ __launch_bounds__(256) void prep_k(
    const float* __restrict__ x, const int* __restrict__ theta,
    unsigned* __restrict__ xIh, unsigned* __restrict__ xTIh,
    int4* __restrict__ bbox, float* __restrict__ out)
{
    const int bid = blockIdx.x;
    const int tx = threadIdx.x, ty = threadIdx.y;
    const int tid = ty * 32 + tx;

    if (bid < 81) {
        __shared__ unsigned tl[32][33];
        const int cx0 = (bid % 9) * 32, cy0 = (bid / 9) * 32;
        #pragma unroll
        for (int dy = 0; dy < 32; dy += 8) {
            const int cy = cy0 + ty + dy, cx = cx0 + tx;
            const int pr = cy - 4, pc = cx - 4;
            unsigned v = 0u;
            if ((unsigned)pr < 256u && (unsigned)pc < 256u) {
                const int p = pr * 256 + pc;
                const unsigned short a = __half_as_ushort(__float2half_rn(x[p]));
                const unsigned short b = __half_as_ushort(__float2half_rn(x[p + 65536]));
                v = (unsigned)a | ((unsigned)b << 16);
            }
            if (cy < CH && cx < CW) xIh[cy * CW + cx] = v;
            tl[ty + dy][tx] = v;
        }
        __syncthreads();
        #pragma unroll
        for (int dy = 0; dy < 32; dy += 8) {
            const int rp = cx0 + ty + dy, cp = cy0 + tx;
            if (rp < CH && cp < CW) xTIh[rp * CW + cp] = tl[tx][ty + dy];
        }
    } else if (bid < 98) {
        const int tuple = (bid - 81) * 256 + tid;
        if (tuple < NTUPLE) {
            const int tg  = tuple / (NJB * NIB), rem = tuple - tg * (NJB * NIB);
            const int jb  = rem / NIB,   ib  = rem - jb * NIB;
            const float thA = (float)theta[tg * 2]     * DEG2RAD;
            const float thB = (float)theta[tg * 2 + 1] * DEG2RAD;
            const float cA = cosf(thA), sA = sinf(thA);
            const float cB = cosf(thB), sB = sinf(thB);
            const float xjm = fmaf((float)(jb * 64),      STEP, -1.0f);
            const float xjM = fmaf((float)(jb * 64 + 63), STEP, -1.0f);
            const float xim = fmaf((float)(ib * 48),      STEP, -1.0f);
            const float xiM = fmaf((float)(ib * 48 + 47), STEP, -1.0f);
            float ixmin = 1e30f, ixmax = -1e30f, iymin = 1e30f, iymax = -1e30f;
            #pragma unroll
            for (int qq = 0; qq < 8; ++qq) {
                const float cc  = (qq & 4) ? cB : cA;
                const float ss  = (qq & 4) ? sB : sA;
                const float xjc = (qq & 1) ? xjM : xjm;
                const float xic = (qq & 2) ? xiM : xim;
                const float bxq = fmaf(cc,  xjc, 1.0f) * 181.0f;
                const float byq = fmaf(-ss, xjc, 1.0f) * 181.0f;
                const float ixq = fmaf(ss * 181.0f, xic, bxq);
                const float iyq = fmaf(cc * 181.0f, xic, byq);
                ixmin = fminf(ixmin, ixq); ixmax = fmaxf(ixmax, ixq);
                iymin = fminf(iymin, iyq); iymax = fmaxf(iymax, iyq);
            }
            const int caseA = (fabsf(cA) + fabsf(cB) >= fabsf(sA) + fabsf(sB));
            const float Umin = caseA ? iymin : ixmin;
            const float Umax = caseA ? iymax : ixmax;
            const float Vmin = caseA ? ixmin : iymin;
            const int r0 = (int)floorf(Umin) - 1;
            const int c0 = (int)floorf(Vmin) - 1;
            int rows = (int)floorf(Umax) - (int)floorf(Umin) + 4;
            rows = min(rows, TROWS);
            const int nchunk = (rows * 3 + 7) >> 3;         // ceil(rows*96/256)
            const int r0p = r0 - PADB, c0p = c0 - PADB;
            const int tyLast = (nchunk * 256 - 1) / TS2;
            const int safe = (r0p >= -4) && (r0p + tyLast <= 259)
                          && (c0p >= -4) && (c0p <= 164);
            bbox[tuple] = make_int4(r0p, c0p,
                                    nchunk | (safe << 8) | (caseA << 9),
                                    0);
        }
    } else {
        const int idx = (bid - 98) * 256 + tid;             // out: 130680 f32
        if (idx < 32670) ((float4*)out)[idx] = make_float4(0.f, 0.f, 0.f, 0.f);
    }
}

// ---------------- staging: 16B/lane global_load_lds, linear LDS dest -------
template<bool SAFE>
__device__ __forceinline__ void stage_direct(unsigned* tileB,
    const unsigned* __restrict__ srcC,
    int r0p, int c0p, int nchunk, int wid, int lane)
{
    const int B = (r0p + 4) * CW + (c0p + 4);
    for (int h = wid; h < nchunk; h += 8) {
        const int hs   = __builtin_amdgcn_readfirstlane(h);
        const int cell = (hs << 8) + (lane << 2);   // 4 cells / lane, row-pure
        const int tyc  = cell / TS2;                // magic mul (const 96)
        const int txc  = cell - tyc * TS2;
        int idx;
        if (SAFE) {
            idx = tyc * CW + txc + B;
        } else {
            // clamp into 4-wide zero guard: 16B lane-read stays all-guard
            const int rc = min(max(r0p + tyc, -4), 256) + 4;
            const int cc = min(max(c0p + txc, -4), 256) + 4;
            idx = rc * CW + cc;
        }
        GLOAD16(srcC + idx, (char*)tileB + (hs << 10));
    }
}

// ---------------- gather inner loop (6 i-steps, packed-f16 lerp) -----------
// Cells are __half2 {img0, img1}: both images interpolated per pk-f16 op.
template<bool TAIL>
__device__ __forceinline__ void gather6(const unsigned* __restrict__ tl,
    float Uf0, float Vf0, float dU, float dV, int iexc,
    float& a0, float& a1)
{
    __half2 acc = __float2half2_rn(0.0f);
    #pragma unroll
    for (int k = 0; k < 6; ++k) {
        const float Uf = fmaf((float)k, dU, Uf0);   // independent, no chain
        const float Vf = fmaf((float)k, dV, Vf0);
        const float fU = floorf(Uf), fV = floorf(Vf);
        const float wU1 = Uf - fU;
        const float wV1 = Vf - fV;
        // fU*96+fV exact (small non-neg integers); tile-relative already
        const int rel = (int)fmaf(fU, (float)TS2, fV);
        const __half2 x00 = *(const __half2*)(tl + rel);
        const __half2 x01 = *(const __half2*)(tl + rel + 1);
        const __half2 x10 = *(const __half2*)(tl + rel + TS2);
        const __half2 x11 = *(const __half2*)(tl + rel + TS2 + 1);
        const __half2 wv2 = __float2half2_rn(wV1);
        const __half2 wu2 = __float2half2_rn(wU1);
        const __half2 t0 = __hfma2(wv2, __hsub2(x01, x00), x00);
        const __half2 t1 = __hfma2(wv2, __hsub2(x11, x10), x10);
        __half2 v = __hfma2(wu2, __hsub2(t1, t0), t0);
        if (TAIL && k >= iexc) v = __float2half2_rn(0.0f);   // phantom i >= G
        acc = __hadd2(acc, v);
    }
    a0 += __low2float(acc);
    a1 += __high2float(acc);
}

// ---------------- main tiled gather ----------------------------------------
__global__ __launch_bounds__(512) void radon_tile8(
    const unsigned* __restrict__ xIh, const unsigned* __restrict__ xTIh,
    const int*   __restrict__ theta, const int4* __restrict__ bbox,
    float* __restrict__ out)
{
    __shared__ unsigned tile[NTILE];       // 35,840 B -> 4 blocks/CU

    const int blk  = blockIdx.x;           // 0..539
    const int z    = blockIdx.y;           // 0..3, handles ib = 2z, 2z+1
    const int tg   = blk / NJB;
    const int jb   = blk - tg * NJB;
    const int tid  = threadIdx.x;
    const int lane = tid & 63;
    const int wid  = tid >> 6;             // 0..7
    const int a    = wid >> 2;             // angle of pair
    const int wq   = wid & 3;              // j quarter (16)
    const int jl   = lane & 15;            // j lane
    const int kk   = lane >> 4;            // i 12-group (0..3)

    const int t = tg * 2 + a;
    const float th = (float)theta[t] * DEG2RAD;
    const float c = cosf(th), s = sinf(th);
    const float s181 = s * 181.0f, c181 = c * 181.0f;

    const int   j  = jb * 64 + wq * 16 + jl;   // phantom j >= 363 ok
    const float xj = fmaf((float)j, STEP, -1.0f);
    const float bx = fmaf(c,  xj, 1.0f) * 181.0f;
    const float by = fmaf(-s, xj, 1.0f) * 181.0f;

    const float fiofs = (float)(kk * 12);

    // ---- per-pair uniforms (case identical across the subtiles) ----
    const int tb = (tg * NJB + jb) * NIB + z * 2;
    const int caseA = (__builtin_amdgcn_readfirstlane(bbox[tb].z) >> 9) & 1;
    const unsigned* __restrict__ srcC = caseA ? xIh : xTIh;

    const float slopeU = caseA ? c181 : s181;
    const float slopeV = caseA ? s181 : c181;
    const float dU = slopeU * STEP;
    const float dV = slopeV * STEP;
    const float U00 = (caseA ? by : bx) - slopeU;
    const float V00 = (caseA ? bx : by) - slopeV;

    float a0 = 0.f, a1 = 0.f;

    #pragma unroll
    for (int ibi = 0; ibi < 2; ++ibi) {
        const int ib = z * 2 + ibi;
        const int4 bb = bbox[tb + ibi];
        const int r0p    = __builtin_amdgcn_readfirstlane(bb.x);
        const int c0p    = __builtin_amdgcn_readfirstlane(bb.y);
        const int flags  = __builtin_amdgcn_readfirstlane(bb.z);
        const int nchunk = flags & 255;
        const int safe   = (flags >> 8) & 1;

        __syncthreads();                   // previous tile fully consumed

        if (safe) stage_direct<true >(tile, srcC, r0p, c0p, nchunk, wid, lane);
        else      stage_direct<false>(tile, srcC, r0p, c0p, nchunk, wid, lane);
        __syncthreads();                   // drains vmcnt -> tile ready

        // ---- gather: 12 samples/lane as 2x gather6, tile-relative coords --
        const int i0 = ib * 48;
        const float r0f = (float)(r0p + PADB);   // integer subtract: exact
        const float c0f = (float)(c0p + PADB);
        const float fi  = (float)i0 + fiofs;
        const float Uf1 = fmaf(dU, fi, U00) - r0f;
        const float Vf1 = fmaf(dV, fi, V00) - c0f;
        const float Uf2 = fmaf(dU, 6.0f, Uf1);
        const float Vf2 = fmaf(dV, 6.0f, Vf1);
        const int ibase = i0 + kk * 12;

        if (i0 + 47 < G) {                 // block-uniform
            gather6<false>(tile, Uf1, Vf1, dU, dV, 6, a0, a1);
            gather6<false>(tile, Uf2, Vf2, dU, dV, 6, a0, a1);
        } else {
            gather6<true>(tile, Uf1, Vf1, dU, dV, G - ibase,     a0, a1);
            gather6<true>(tile, Uf2, Vf2, dU, dV, G - ibase - 6, a0, a1);
        }
    }

    // ---- reduce i-groups (lanes jl, jl+16, jl+32, jl+48) via shfl ----
    float vx = a0;
    float vy = a1;
    vx += __shfl_xor(vx, 16);
    vy += __shfl_xor(vy, 16);
    vx += __shfl_xor(vx, 32);
    vy += __shfl_xor(vy, 32);

    if (lane < 16 && j < G) {
        atomicAdd(&out[j * NT + t],          vx);   // n = 0
        atomicAdd(&out[G * NT + j * NT + t], vy);   // n = 1
    }
}

extern "C" void kernel_launch(void* const* d_in, const int* in_sizes, int n_in,
                              void* d_out, int out_size, void* d_ws, size_t ws_size,
                              hipStream_t stream) {
    const float* x     = (const float*)d_in[0];
    const int*   theta = (const int*)d_in[1];
    float*       out   = (float*)d_out;

    const size_t XIH_OFF  = 0;
    const size_t XTIH_OFF = (size_t)CH * CW * 4;                 // 278,784
    const size_t BBOX_OFF = 2 * XTIH_OFF;                        // 557,568
    const size_t NEED     = BBOX_OFF + (size_t)NTUPLE * 16;      // ~627 KB

    if (ws_size < NEED) {   // fallback: known-good gather kernel
        hipLaunchKernelGGL(radon_fwd, dim3(NT * NJBF), dim3(64, 4), 0, stream,
                           x, theta, out);
        return;
    }

    unsigned* xIh  = (unsigned*)((char*)d_ws + XIH_OFF);
    unsigned* xTIh = (unsigned*)((char*)d_ws + XTIH_OFF);
    int4*     bbox = (int4*)((char*)d_ws + BBOX_OFF);

    hipLaunchKernelGGL(prep_k, dim3(226), dim3(32, 8), 0, stream,
                       x, theta, xIh, xTIh, bbox, out);
    hipLaunchKernelGGL(radon_tile8, dim3(540, 4), dim3(512), 0, stream,
                       xIh, xTIh, theta, bbox, out);
}

// Round 9
// 39.105 us; speedup vs baseline: 1.0789x; 1.0789x over previous
//
#include <hip/hip_runtime.h>
#include <hip/hip_fp16.h>
#include <math.h>

// Radon forward, exact reference semantics (rotated-lattice bilinear gather).
//
// Round-15 changes vs round 14 (42.2 us -- REGRESSION; r13 34.1 us champion):
//  * Post-mortem r14: halving stage events but also halving independent
//    block streams (8->4/CU) LOST 8 us -> wall is stall-overlap-limited by
//    the stage->vmcnt(0)->barrier convoy, not by event count per se.
//  * This round removes the convoy ENTIRELY: the f16x2 canvases are 558 KB
//    total -- L2-resident on every XCD (4 MiB). Gather taps directly from
//    global/L2 (guide Common-mistake #7: don't LDS-stage what L2 fits):
//      - per sample: one base addr + 4 global_load_dword at imm offsets
//        (0/4/1056/1060), clamp-to-guard via fminf/fmaxf -> v_med3_f32
//        (OOB taps read guaranteed-zero 4-wide guard ring)
//      - r13's proven packed-f16 lerp; f16 accumulate per 6 taps (proven
//        precision), flush to f32
//      - NO barriers, NO staging, NO bbox table, NO atomics, NO out-zero
//  * Block = (t, jb of 32 j) x 8 i-chunks; 2160 blocks x 256 threads;
//    each thread 46 strided taps (i = chunk + 8k). Free-running waves,
//    32/CU -- latency hidden by TLP instead of tile scheduling.
//  * prep shrinks to canvas packing only (81 blocks).

#define G       363
#define NT      180
#define STEP    (2.0f / 362.0f)
#define DEG2RAD 0.017453292519943295f

#define NJB     12          // j-blocks of 32
#define NJBF    6           // fallback j-blocks of 64
#define CW      264         // canvas cols (4 guard + 256 + 4 guard)
#define CH      264         // canvas rows

// ---------------- fallback gather kernel (known-good, round 1) -------------
__global__ __launch_bounds__(256) void radon_fwd(
    const float* __restrict__ x, const int* __restrict__ theta,
    float* __restrict__ out)
{
    const int t = blockIdx.x / NJBF, jb = blockIdx.x % NJBF;
    const int jl = threadIdx.x, chunk = threadIdx.y;
    const int j = jb * 64 + jl;
    const float th = (float)theta[t] * DEG2RAD;
    const float c = cosf(th), s = sinf(th);
    const float xj = fmaf((float)j, STEP, -1.0f);
    const float s181 = s * 181.0f, c181 = c * 181.0f;
    const float bx = fmaf(c, xj, 1.0f) * 181.0f;
    const float by = fmaf(-s, xj, 1.0f) * 181.0f;
    const float* img0 = x;
    const float* img1 = x + 65536;
    float acc0 = 0.f, acc1 = 0.f;
    for (int i = chunk; i < G; i += 4) {
        const float xi = fmaf((float)i, STEP, -1.0f);
        const float ix = fmaf(s181, xi, bx);
        const float iy = fmaf(c181, xi, by);
        const float fx = floorf(ix), fy = floorf(iy);
        const int ix0 = (int)fx, iy0 = (int)fy;
        const float wx1 = ix - fx, wy1 = iy - fy;
        const float wx0 = 1.f - wx1, wy0 = 1.f - wy1;
        const int cc0 = ix0 - 53, cc1 = cc0 + 1, rr0 = iy0 - 53, rr1 = rr0 + 1;
        const float wxa = ((unsigned)cc0 < 256u) ? wx0 : 0.f;
        const float wxb = ((unsigned)cc1 < 256u) ? wx1 : 0.f;
        const float wya = ((unsigned)rr0 < 256u) ? wy0 : 0.f;
        const float wyb = ((unsigned)rr1 < 256u) ? wy1 : 0.f;
        const int c0c = min(max(cc0, 0), 255), c1c = min(max(cc1, 0), 255);
        const int r0b = min(max(rr0, 0), 255) << 8, r1b = min(max(rr1, 0), 255) << 8;
        const float w00 = wya * wxa, w01 = wya * wxb, w10 = wyb * wxa, w11 = wyb * wxb;
        acc0 = fmaf(img0[r0b + c0c], w00, acc0);
        acc0 = fmaf(img0[r0b + c1c], w01, acc0);
        acc0 = fmaf(img0[r1b + c0c], w10, acc0);
        acc0 = fmaf(img0[r1b + c1c], w11, acc0);
        acc1 = fmaf(img1[r0b + c0c], w00, acc1);
        acc1 = fmaf(img1[r0b + c1c], w01, acc1);
        acc1 = fmaf(img1[r1b + c0c], w10, acc1);
        acc1 = fmaf(img1[r1b + c1c], w11, acc1);
    }
    __shared__ float red[2][4][64];
    red[0][chunk][jl] = acc0;
    red[1][chunk][jl] = acc1;
    __syncthreads();
    if (threadIdx.y < 2 && j < G) {
        const int n = threadIdx.y;
        out[n * (G * NT) + j * NT + t] =
            red[n][0][jl] + red[n][1][jl] + red[n][2][jl] + red[n][3][jl];
    }
}

// ------------- prep: f16x2 canvases only (guarded, normal + transposed) ----
__global__ __launch_bounds__(256) void prep_k(
    const float* __restrict__ x,
    unsigned* __restrict__ xIh, unsigned* __restrict__ xTIh)
{
    const int bid = blockIdx.x;            // 0..80 (9x9 grid of 32x32)
    const int tx = threadIdx.x, ty = threadIdx.y;

    __shared__ unsigned tl[32][33];
    const int cx0 = (bid % 9) * 32, cy0 = (bid / 9) * 32;
    #pragma unroll
    for (int dy = 0; dy < 32; dy += 8) {
        const int cy = cy0 + ty + dy, cx = cx0 + tx;
        const int pr = cy - 4, pc = cx - 4;
        unsigned v = 0u;
        if ((unsigned)pr < 256u && (unsigned)pc < 256u) {
            const int p = pr * 256 + pc;
            const unsigned short a = __half_as_ushort(__float2half_rn(x[p]));
            const unsigned short b = __half_as_ushort(__float2half_rn(x[p + 65536]));
            v = (unsigned)a | ((unsigned)b << 16);
        }
        if (cy < CH && cx < CW) xIh[cy * CW + cx] = v;
        tl[ty + dy][tx] = v;
    }
    __syncthreads();
    #pragma unroll
    for (int dy = 0; dy < 32; dy += 8) {
        const int rp = cx0 + ty + dy, cp = cy0 + tx;
        if (rp < CH && cp < CW) xTIh[rp * CW + cp] = tl[tx][ty + dy];
    }
}

// ---------------- per-tap body (packed-f16 lerp from L2) -------------------
__device__ __forceinline__ __half2 tap(const unsigned* __restrict__ cv,
    float fi, float dU, float dV, float U00, float V00)
{
    const float U = fmaf(dU, fi, U00);      // canvas-row coordinate
    const float V = fmaf(dV, fi, V00);      // canvas-col coordinate
    const float fU = floorf(U), fV = floorf(V);
    const float wU1 = U - fU, wV1 = V - fV;
    // clamp into 4-wide zero guard: any clamped/OOB tap reads zeros, and
    // its (arbitrary) weight multiplies zero -> exact OOB semantics.
    const float fUc = fminf(fmaxf(fU, 0.0f), 262.0f);   // v_med3_f32
    const float fVc = fminf(fmaxf(fV, 0.0f), 262.0f);
    const int rel = (int)fmaf(fUc, (float)CW, fVc);      // exact (< 2^24)
    const __half2* p = (const __half2*)(cv + rel);       // 1 base addr,
    const __half2 x00 = p[0];                            // 4 dword loads at
    const __half2 x01 = p[1];                            // imm offsets
    const __half2 x10 = p[CW];
    const __half2 x11 = p[CW + 1];
    const __half2 wv2 = __float2half2_rn(wV1);
    const __half2 wu2 = __float2half2_rn(wU1);
    const __half2 t0 = __hfma2(wv2, __hsub2(x01, x00), x00);
    const __half2 t1 = __hfma2(wv2, __hsub2(x11, x10), x10);
    return __hfma2(wu2, __hsub2(t1, t0), t0);
}

// ---------------- main gather: direct from L2, no LDS tiles ----------------
__global__ __launch_bounds__(256) void radon_l2(
    const unsigned* __restrict__ xIh, const unsigned* __restrict__ xTIh,
    const int* __restrict__ theta, float* __restrict__ out)
{
    const int blk  = blockIdx.x;           // 0..2159
    const int t    = blk / NJB;
    const int jb   = blk - t * NJB;
    const int tid  = threadIdx.x;
    const int lane = tid & 63;
    const int wid  = tid >> 6;             // 0..3
    const int jl   = lane & 31;            // j lane
    const int kc   = lane >> 5;            // chunk low bit
    const int chunk = wid * 2 + kc;        // 0..7 (i stride 8)

    const float th = (float)theta[t] * DEG2RAD;
    const float c = cosf(th), s = sinf(th);
    const float s181 = s * 181.0f, c181 = c * 181.0f;

    const int   j  = jb * 32 + jl;         // phantom j >= 363 ok (not stored)
    const float xj = fmaf((float)j, STEP, -1.0f);
    const float bx = fmaf(c,  xj, 1.0f) * 181.0f;
    const float by = fmaf(-s, xj, 1.0f) * 181.0f;

    const int caseA = (fabsf(c) >= fabsf(s));
    const unsigned* __restrict__ cv = caseA ? xIh : xTIh;

    const float slopeU = caseA ? c181 : s181;
    const float slopeV = caseA ? s181 : c181;
    const float dU = slopeU * STEP;
    const float dV = slopeV * STEP;
    // U(fi) = slopeU*(fi*STEP - 1) + uBase - 49 (canvas coords, guard 4,
    // PADB 53 folded): U00 = uBase - slopeU - 49.
    const float U00 = (caseA ? by : bx) - slopeU - 49.0f;
    const float V00 = (caseA ? bx : by) - slopeV - 49.0f;

    float a0 = 0.f, a1 = 0.f;

    // main: 7 groups of 6 taps (i = chunk + 8k, k=0..41; all i <= 335 < G)
    float fig = (float)chunk;
    for (int g = 0; g < 7; ++g) {
        __half2 acc = __float2half2_rn(0.0f);
        #pragma unroll
        for (int k = 0; k < 6; ++k) {
            acc = __hadd2(acc, tap(cv, fig + (float)(k * 8), dU, dV, U00, V00));
        }
        a0 += __low2float(acc);
        a1 += __high2float(acc);
        fig += 48.0f;
    }
    // tail: k = 42..45 -> i = chunk + 336..chunk + 360, masked at i >= G
    {
        __half2 acc = __float2half2_rn(0.0f);
        #pragma unroll
        for (int k = 42; k < 46; ++k) {
            const int i = chunk + k * 8;
            if (i < G)
                acc = __hadd2(acc, tap(cv, (float)i, dU, dV, U00, V00));
        }
        a0 += __low2float(acc);
        a1 += __high2float(acc);
    }

    // ---- reduce: kc pairs in-wave, then 4 waves via tiny LDS ----
    a0 += __shfl_xor(a0, 32);
    a1 += __shfl_xor(a1, 32);

    __shared__ float red[2][4][32];
    if (lane < 32) {
        red[0][wid][jl] = a0;
        red[1][wid][jl] = a1;
    }
    __syncthreads();

    if (tid < 64) {
        const int n = tid >> 5, jj = tid & 31;
        const float v = red[n][0][jj] + red[n][1][jj]
                      + red[n][2][jj] + red[n][3][jj];
        const int jo = jb * 32 + jj;
        if (jo < G)
            out[(n * G + jo) * NT + t] = v;
    }
}

extern "C" void kernel_launch(void* const* d_in, const int* in_sizes, int n_in,
                              void* d_out, int out_size, void* d_ws, size_t ws_size,
                              hipStream_t stream) {
    const float* x     = (const float*)d_in[0];
    const int*   theta = (const int*)d_in[1];
    float*       out   = (float*)d_out;

    const size_t XIH_OFF  = 0;
    const size_t XTIH_OFF = (size_t)CH * CW * 4;                 // 278,784
    const size_t NEED     = 2 * XTIH_OFF;                        // 557,568 B

    if (ws_size < NEED) {   // fallback: known-good gather kernel
        hipLaunchKernelGGL(radon_fwd, dim3(NT * NJBF), dim3(64, 4), 0, stream,
                           x, theta, out);
        return;
    }

    unsigned* xIh  = (unsigned*)((char*)d_ws + XIH_OFF);
    unsigned* xTIh = (unsigned*)((char*)d_ws + XTIH_OFF);

    hipLaunchKernelGGL(prep_k, dim3(81), dim3(32, 8), 0, stream,
                       x, xIh, xTIh);
    hipLaunchKernelGGL(radon_l2, dim3(NT * NJB), dim3(256), 0, stream,
                       xIh, xTIh, theta, out);
}

// Round 10
// 33.191 us; speedup vs baseline: 1.2711x; 1.1782x over previous
//
#include <hip/hip_runtime.h>
#include <hip/hip_fp16.h>
#include <math.h>

// Radon forward, exact reference semantics (rotated-lattice bilinear gather).
//
// Round-16 changes vs round 15 (39.1 us; L2-direct REGRESSION; r13=34.1 us
// champion):
//  * Post-mortem r15: scattered VMEM gather slower than LDS path. r10/r11/
//    r14/r15 triangulate: per-sample pipes ~8 us, r13 wall ~28 us, and every
//    BLOCK-BARRIER variant pays the same stage->vmcnt(0)->barrier convoy tax.
//  * This round: BARRIER-FREE wave-private tiles. Each wave owns a private
//    32x32-cell (4 KB) LDS region: 16j x 24i at a single angle spans
//    sqrt(15^2+23^2)+4 ~= 31.5 <= 32 rows/cols (corners use the identical
//    fmaf chain as samples; +-1 slack absorbs rounding). Stage = 4x
//    global_load_lds (shift-only addressing); sync = wave-local
//    s_waitcnt vmcnt(0) / lgkmcnt(0) + sched_barrier(0) (rule #18).
//    ZERO __syncthreads in the main loop -- waves free-run, stage latency
//    hides behind ~8 waves/SIMD instead of convoying.
//  * Single angle per wave -> no pair-union bbox slop; bbox = 8 fmaf +
//    2 min-trees in-kernel (no table, no prep blocks).
//  * Block = (t, 32j), 4 waves (2 wj x 2 wi), 8 subtiles of 24i per wave;
//    direct store (no atomics, no out-zero). LDS 16.9 KB -> 8 blocks/CU
//    x 4 waves = 32 waves/CU.
//  * Inner tap loop identical to r13 (packed-f16 lerp, proven precision).

#define G       363
#define NT      180
#define PADB    53
#define STEP    (2.0f / 362.0f)
#define DEG2RAD 0.017453292519943295f

#define TSW     32          // wave-tile row length (u32 cells)
#define NJB     12          // j-blocks of 32
#define NJBF    6           // fallback j-blocks of 64
#define CW      264         // canvas cols (4 guard + 256 + 4 guard)
#define CH      264         // canvas rows

#define GLOAD16(gp, lp) __builtin_amdgcn_global_load_lds(                     \
    (const __attribute__((address_space(1))) void*)(gp),                      \
    (__attribute__((address_space(3))) void*)(lp), 16, 0, 0)

// ---------------- fallback gather kernel (known-good, round 1) -------------
__global__ __launch_bounds__(256) void radon_fwd(
    const float* __restrict__ x, const int* __restrict__ theta,
    float* __restrict__ out)
{
    const int t = blockIdx.x / NJBF, jb = blockIdx.x % NJBF;
    const int jl = threadIdx.x, chunk = threadIdx.y;
    const int j = jb * 64 + jl;
    const float th = (float)theta[t] * DEG2RAD;
    const float c = cosf(th), s = sinf(th);
    const float xj = fmaf((float)j, STEP, -1.0f);
    const float s181 = s * 181.0f, c181 = c * 181.0f;
    const float bx = fmaf(c, xj, 1.0f) * 181.0f;
    const float by = fmaf(-s, xj, 1.0f) * 181.0f;
    const float* img0 = x;
    const float* img1 = x + 65536;
    float acc0 = 0.f, acc1 = 0.f;
    for (int i = chunk; i < G; i += 4) {
        const float xi = fmaf((float)i, STEP, -1.0f);
        const float ix = fmaf(s181, xi, bx);
        const float iy = fmaf(c181, xi, by);
        const float fx = floorf(ix), fy = floorf(iy);
        const int ix0 = (int)fx, iy0 = (int)fy;
        const float wx1 = ix - fx, wy1 = iy - fy;
        const float wx0 = 1.f - wx1, wy0 = 1.f - wy1;
        const int cc0 = ix0 - 53, cc1 = cc0 + 1, rr0 = iy0 - 53, rr1 = rr0 + 1;
        const float wxa = ((unsigned)cc0 < 256u) ? wx0 : 0.f;
        const float wxb = ((unsigned)cc1 < 256u) ? wx1 : 0.f;
        const float wya = ((unsigned)rr0 < 256u) ? wy0 : 0.f;
        const float wyb = ((unsigned)rr1 < 256u) ? wy1 : 0.f;
        const int c0c = min(max(cc0, 0), 255), c1c = min(max(cc1, 0), 255);
        const int r0b = min(max(rr0, 0), 255) << 8, r1b = min(max(rr1, 0), 255) << 8;
        const float w00 = wya * wxa, w01 = wya * wxb, w10 = wyb * wxa, w11 = wyb * wxb;
        acc0 = fmaf(img0[r0b + c0c], w00, acc0);
        acc0 = fmaf(img0[r0b + c1c], w01, acc0);
        acc0 = fmaf(img0[r1b + c0c], w10, acc0);
        acc0 = fmaf(img0[r1b + c1c], w11, acc0);
        acc1 = fmaf(img1[r0b + c0c], w00, acc1);
        acc1 = fmaf(img1[r0b + c1c], w01, acc1);
        acc1 = fmaf(img1[r1b + c0c], w10, acc1);
        acc1 = fmaf(img1[r1b + c1c], w11, acc1);
    }
    __shared__ float red[2][4][64];
    red[0][chunk][jl] = acc0;
    red[1][chunk][jl] = acc1;
    __syncthreads();
    if (threadIdx.y < 2 && j < G) {
        const int n = threadIdx.y;
        out[n * (G * NT) + j * NT + t] =
            red[n][0][jl] + red[n][1][jl] + red[n][2][jl] + red[n][3][jl];
    }
}

// ------------- prep: f16x2 canvases only (guarded, normal + transposed) ----
__global__ __launch_bounds__(256) void prep_k(
    const float* __restrict__ x,
    unsigned* __restrict__ xIh, unsigned* __restrict__ xTIh)
{
    const int bid = blockIdx.x;            // 0..80 (9x9 grid of 32x32)
    const int tx = threadIdx.x, ty = threadIdx.y;

    __shared__ unsigned tl[32][33];
    const int cx0 = (bid % 9) * 32, cy0 = (bid / 9) * 32;
    #pragma unroll
    for (int dy = 0; dy < 32; dy += 8) {
        const int cy = cy0 + ty + dy, cx = cx0 + tx;
        const int pr = cy - 4, pc = cx - 4;
        unsigned v = 0u;
        if ((unsigned)pr < 256u && (unsigned)pc < 256u) {
            const int p = pr * 256 + pc;
            const unsigned short a = __half_as_ushort(__float2half_rn(x[p]));
            const unsigned short b = __half_as_ushort(__float2half_rn(x[p + 65536]));
            v = (unsigned)a | ((unsigned)b << 16);
        }
        if (cy < CH && cx < CW) xIh[cy * CW + cx] = v;
        tl[ty + dy][tx] = v;
    }
    __syncthreads();
    #pragma unroll
    for (int dy = 0; dy < 32; dy += 8) {
        const int rp = cx0 + ty + dy, cp = cy0 + tx;
        if (rp < CH && cp < CW) xTIh[rp * CW + cp] = tl[tx][ty + dy];
    }
}

// ---------------- staging: 4x global_load_lds into wave-private 32x32 ------
template<bool SAFE>
__device__ __forceinline__ void stage32(char* tileW_b,
    const unsigned* __restrict__ srcC, int r0p, int c0p, int lane)
{
    const int ty0 = lane >> 3;             // 0..7
    const int tx  = (lane & 7) << 2;       // 0,4,...,28 (4 cells/lane)
    #pragma unroll
    for (int u = 0; u < 4; ++u) {
        const int ty = ty0 + (u << 3);
        int idx;
        if (SAFE) {
            idx = (r0p + 4 + ty) * CW + (c0p + 4 + tx);
        } else {
            // clamp into 4-wide zero guard: OOB taps read guaranteed zeros
            const int rc = min(max(r0p + ty, -4), 256) + 4;
            const int cc = min(max(c0p + tx, -4), 256) + 4;
            idx = rc * CW + cc;
        }
        GLOAD16(srcC + idx, tileW_b + (u << 10));
    }
}

// ---------------- gather inner loop (6 i-steps, packed-f16 lerp) -----------
template<bool TAIL>
__device__ __forceinline__ void gather6(const unsigned* __restrict__ tl,
    float Uf0, float Vf0, float dU, float dV, int iexc,
    float& a0, float& a1)
{
    __half2 acc = __float2half2_rn(0.0f);
    #pragma unroll
    for (int k = 0; k < 6; ++k) {
        const float Uf = fmaf((float)k, dU, Uf0);   // independent, no chain
        const float Vf = fmaf((float)k, dV, Vf0);
        const float fU = floorf(Uf), fV = floorf(Vf);
        const float wU1 = Uf - fU;
        const float wV1 = Vf - fV;
        // fU*32+fV exact small ints; rel in [0, 1024)
        const int rel = (int)fmaf(fU, (float)TSW, fV);
        const __half2 x00 = *(const __half2*)(tl + rel);
        const __half2 x01 = *(const __half2*)(tl + rel + 1);
        const __half2 x10 = *(const __half2*)(tl + rel + TSW);
        const __half2 x11 = *(const __half2*)(tl + rel + TSW + 1);
        const __half2 wv2 = __float2half2_rn(wV1);
        const __half2 wu2 = __float2half2_rn(wU1);
        const __half2 t0 = __hfma2(wv2, __hsub2(x01, x00), x00);
        const __half2 t1 = __hfma2(wv2, __hsub2(x11, x10), x10);
        __half2 v = __hfma2(wu2, __hsub2(t1, t0), t0);
        if (TAIL && k >= iexc) v = __float2half2_rn(0.0f);   // phantom i >= G
        acc = __hadd2(acc, v);
    }
    a0 += __low2float(acc);
    a1 += __high2float(acc);
}

// ---------------- main gather: barrier-free wave-private tiles -------------
__global__ __launch_bounds__(256) void radon_wv(
    const unsigned* __restrict__ xIh, const unsigned* __restrict__ xTIh,
    const int* __restrict__ theta, float* __restrict__ out)
{
    __shared__ unsigned tile[4 * TSW * TSW];   // 4 waves x 4 KB, private
    __shared__ float red[4][2][16];

    const int blk  = blockIdx.x;           // 0..2159
    const int t    = blk / NJB;
    const int jb   = blk - t * NJB;
    const int tid  = threadIdx.x;
    const int lane = tid & 63;
    const int wid  = tid >> 6;             // 0..3
    const int wj   = wid & 1;              // j half (16)
    const int wi   = wid >> 1;             // i half (192)
    const int jl   = lane & 15;            // j lane
    const int kk   = lane >> 4;            // i 6-group (0..3)

    unsigned* tileW = tile + wid * (TSW * TSW);
    char*     tileW_b = (char*)tileW;

    const float th = (float)theta[t] * DEG2RAD;
    const float c = cosf(th), s = sinf(th);
    const float s181 = s * 181.0f, c181 = c * 181.0f;

    const int caseA = (fabsf(c) >= fabsf(s));
    const unsigned* __restrict__ srcC = caseA ? xIh : xTIh;

    const float slopeU = caseA ? c181 : s181;
    const float slopeV = caseA ? s181 : c181;
    const float dU = slopeU * STEP;
    const float dV = slopeV * STEP;

    // per-lane sample base (U(i) = dU*i + U00L, padded-grid coords)
    const int   j  = jb * 32 + wj * 16 + jl;   // phantom j >= 363 ok
    const float xj = fmaf((float)j, STEP, -1.0f);
    const float bx = fmaf(c,  xj, 1.0f) * 181.0f;
    const float by = fmaf(-s, xj, 1.0f) * 181.0f;
    const float U00L = (caseA ? by : bx) - slopeU;
    const float V00L = (caseA ? bx : by) - slopeV;

    // wave-corner bases (identical fmaf chain, j endpoints of this wave)
    const int   j0  = jb * 32 + wj * 16;
    const float xjm = fmaf((float)j0,        STEP, -1.0f);
    const float xjM = fmaf((float)(j0 + 15), STEP, -1.0f);
    const float bxm = fmaf(c,  xjm, 1.0f) * 181.0f;
    const float bym = fmaf(-s, xjm, 1.0f) * 181.0f;
    const float bxM = fmaf(c,  xjM, 1.0f) * 181.0f;
    const float byM = fmaf(-s, xjM, 1.0f) * 181.0f;
    const float U00m = (caseA ? bym : bxm) - slopeU;
    const float U00M = (caseA ? byM : bxM) - slopeU;
    const float V00m = (caseA ? bxm : bym) - slopeV;
    const float V00M = (caseA ? bxM : byM) - slopeV;

    const float fiofs = (float)(kk * 6);

    float a0 = 0.f, a1 = 0.f;

    for (int sub = 0; sub < 8; ++sub) {
        const int i0 = (wi * 8 + sub) * 24;
        const float fi0 = (float)i0, fi1 = (float)(i0 + 23);

        // ---- bbox mins (4 corners each axis; same chain as samples) ----
        const float Umin = fminf(fminf(fmaf(dU, fi0, U00m), fmaf(dU, fi0, U00M)),
                                 fminf(fmaf(dU, fi1, U00m), fmaf(dU, fi1, U00M)));
        const float Vmin = fminf(fminf(fmaf(dV, fi0, V00m), fmaf(dV, fi0, V00M)),
                                 fminf(fmaf(dV, fi1, V00m), fmaf(dV, fi1, V00M)));
        const int r0 = __builtin_amdgcn_readfirstlane((int)floorf(Umin) - 1);
        const int c0 = __builtin_amdgcn_readfirstlane((int)floorf(Vmin) - 1);
        const int r0p = r0 - PADB, c0p = c0 - PADB;

        // ---- fence: prior subtile's ds_reads done before overwrite ----
        asm volatile("s_waitcnt lgkmcnt(0)" ::: "memory");
        __builtin_amdgcn_sched_barrier(0);

        if (r0p >= -4 && r0p <= 228 && c0p >= -4 && c0p <= 228)
            stage32<true >(tileW_b, srcC, r0p, c0p, lane);
        else
            stage32<false>(tileW_b, srcC, r0p, c0p, lane);

        // ---- wave-local drain; NO block barrier ----
        asm volatile("s_waitcnt vmcnt(0)" ::: "memory");
        __builtin_amdgcn_sched_barrier(0);

        // ---- gather 6 taps/lane, tile-relative coords ----
        const float fi  = fi0 + fiofs;
        const float Uf0 = fmaf(dU, fi, U00L) - (float)r0;
        const float Vf0 = fmaf(dV, fi, V00L) - (float)c0;
        const int ibase = i0 + kk * 6;

        if (i0 + 23 < G) {
            gather6<false>(tileW, Uf0, Vf0, dU, dV, 6, a0, a1);
        } else {
            gather6<true>(tileW, Uf0, Vf0, dU, dV, G - ibase, a0, a1);
        }
    }

    // ---- reduce kk groups in-wave, wi halves across waves ----
    a0 += __shfl_xor(a0, 16); a1 += __shfl_xor(a1, 16);
    a0 += __shfl_xor(a0, 32); a1 += __shfl_xor(a1, 32);

    if (lane < 16) {
        red[wid][0][lane] = a0;
        red[wid][1][lane] = a1;
    }
    __syncthreads();

    if (tid < 64) {
        const int n = tid >> 5, jj = tid & 31;
        const int wj2 = jj >> 4, jl2 = jj & 15;
        const float v = red[wj2][n][jl2] + red[wj2 + 2][n][jl2];
        const int jo = jb * 32 + jj;
        if (jo < G)
            out[(n * G + jo) * NT + t] = v;
    }
}

extern "C" void kernel_launch(void* const* d_in, const int* in_sizes, int n_in,
                              void* d_out, int out_size, void* d_ws, size_t ws_size,
                              hipStream_t stream) {
    const float* x     = (const float*)d_in[0];
    const int*   theta = (const int*)d_in[1];
    float*       out   = (float*)d_out;

    const size_t XIH_OFF  = 0;
    const size_t XTIH_OFF = (size_t)CH * CW * 4;                 // 278,784
    const size_t NEED     = 2 * XTIH_OFF;                        // 557,568 B

    if (ws_size < NEED) {   // fallback: known-good gather kernel
        hipLaunchKernelGGL(radon_fwd, dim3(NT * NJBF), dim3(64, 4), 0, stream,
                           x, theta, out);
        return;
    }

    unsigned* xIh  = (unsigned*)((char*)d_ws + XIH_OFF);
    unsigned* xTIh = (unsigned*)((char*)d_ws + XTIH_OFF);

    hipLaunchKernelGGL(prep_k, dim3(81), dim3(32, 8), 0, stream,
                       x, xIh, xTIh);
    hipLaunchKernelGGL(radon_wv, dim3(NT * NJB), dim3(256), 0, stream,
                       xIh, xTIh, theta, out);
}